// Round 8
// baseline (830.016 us; speedup 1.0000x reference)
//
#include <hip/hip_runtime.h>

typedef unsigned short u16;
using u16x8  = __attribute__((ext_vector_type(8))) unsigned short;
using bf16x8 = __attribute__((ext_vector_type(8))) __bf16;
using f32x4  = __attribute__((ext_vector_type(4))) float;

#define NKVAL 32768
#define NQVAL 262144
#define EVAL  524288

__device__ __forceinline__ u16 f2bf(float f) {
  unsigned u = __float_as_uint(f);
  u = (u + 0x7fffu + ((u >> 16) & 1u)) >> 16;   // RNE
  return (u16)u;
}
__device__ __forceinline__ float bf2f(u16 h) {
  return __uint_as_float(((unsigned)h) << 16);
}
__device__ __forceinline__ void gl2lds16(const u16* g, u16* l) {
  __builtin_amdgcn_global_load_lds((const __attribute__((address_space(1))) void*)g,
                                   (__attribute__((address_space(3))) void*)l, 16, 0, 0);
}

// ---------------- int degree ----------------
__global__ __launch_bounds__(256) void degcnt_k(const int* __restrict__ dst, int* __restrict__ cnt) {
  int e = blockIdx.x * 256 + threadIdx.x;
  if (e < EVAL) atomicAdd(&cnt[dst[e]], 1);
}

// ---------------- exclusive scan over cnt[NKVAL] -> off[NKVAL+1], single block ----------------
__global__ __launch_bounds__(1024) void scan_k(const int* __restrict__ cnt, int* __restrict__ off) {
  __shared__ int part[1024];
  const int t = threadIdx.x;
  const int base = t * 32;
  int local[32];
  int s = 0;
#pragma unroll
  for (int i = 0; i < 32; i++) { local[i] = s; s += cnt[base + i]; }
  part[t] = s;
  __syncthreads();
  for (int d = 1; d < 1024; d <<= 1) {
    int v = (t >= d) ? part[t - d] : 0;
    __syncthreads();
    part[t] += v;
    __syncthreads();
  }
  int pre = (t == 0) ? 0 : part[t - 1];
#pragma unroll
  for (int i = 0; i < 32; i++) off[base + i] = pre + local[i];
  if (t == 1023) off[NKVAL] = pre + s;
}

// ---------------- scatter edges into CSR-by-dst ----------------
__global__ __launch_bounds__(256) void scatter_k(const int* __restrict__ src, const int* __restrict__ dst,
                                                 const int* __restrict__ off, int* __restrict__ cur,
                                                 int* __restrict__ srcs_sorted) {
  int e = blockIdx.x * 256 + threadIdx.x;
  if (e < EVAL) {
    int d = dst[e];
    int p = atomicAdd(&cur[d], 1);
    srcs_sorted[off[d] + p] = src[e];
  }
}

// ---------------- layer-0 aggregation via CSR (no atomics) ----------------
__global__ __launch_bounds__(256) void agg0_csr(const int* __restrict__ off, const int* __restrict__ srcs,
                                                const float* __restrict__ known, float* __restrict__ m0) {
  int d = blockIdx.x * 256 + threadIdx.x;
  if (d >= NKVAL) return;
  int b = off[d], e = off[d + 1];
  float a0 = 0.f, a1 = 0.f, a2 = 0.f;
  for (int i = b; i < e; i++) {
    int s = srcs[i];
    a0 += known[s * 3 + 0];
    a1 += known[s * 3 + 1];
    a2 += known[s * 3 + 2];
  }
  m0[d * 3 + 0] = a0;
  m0[d * 3 + 1] = a1;
  m0[d * 3 + 2] = a2;
}

// ---------------- K=3 dense: Y = relu((X[/cnt]) @ W[3,512] + b) -> bf16, vectorized ----------------
__global__ __launch_bounds__(256) void k3_dense(const float* __restrict__ X, const int* __restrict__ cnt,
                                                const float* __restrict__ W, const float* __restrict__ Bb,
                                                u16* __restrict__ Y, int M) {
  int id = blockIdx.x * 256 + threadIdx.x;  // M*64 threads, 8 outputs each
  if (id >= M * 64) return;
  int i = id >> 6, j0 = (id & 63) * 8;
  float x0 = X[i * 3 + 0], x1 = X[i * 3 + 1], x2 = X[i * 3 + 2];
  if (cnt) {
    float inv = 1.0f / fmaxf((float)cnt[i], 1.0f);
    x0 *= inv; x1 *= inv; x2 *= inv;
  }
  u16x8 o;
#pragma unroll
  for (int j = 0; j < 8; j++) {
    float v = fmaf(x0, W[j0 + j], Bb[j0 + j]);
    v = fmaf(x1, W[512 + j0 + j], v);
    v = fmaf(x2, W[1024 + j0 + j], v);
    o[j] = f2bf(fmaxf(v, 0.0f));
  }
  *(u16x8*)(Y + (size_t)i * 512 + j0) = o;
}

// ---------------- GCN aggregation via CSR: wave per dst node, regs only ----------------
__global__ __launch_bounds__(256) void agg_csr(const u16* __restrict__ H, const int* __restrict__ off,
                                               const int* __restrict__ srcs, u16* __restrict__ Mo) {
  const int raw = blockIdx.x;
  const int nb = (raw & 7) * 1024 + (raw >> 3);
  const int node = nb * 4 + (threadIdx.x >> 6);
  const int lane = threadIdx.x & 63;
  const int beg = off[node], end = off[node + 1];
  const int c0 = lane * 8;
  float acc[8] = {0, 0, 0, 0, 0, 0, 0, 0};
  int e = beg;
  for (; e + 4 <= end; e += 4) {
    int s0 = srcs[e], s1 = srcs[e + 1], s2 = srcs[e + 2], s3 = srcs[e + 3];
    u16x8 h0 = *(const u16x8*)(H + (size_t)s0 * 512 + c0);
    u16x8 h1 = *(const u16x8*)(H + (size_t)s1 * 512 + c0);
    u16x8 h2 = *(const u16x8*)(H + (size_t)s2 * 512 + c0);
    u16x8 h3 = *(const u16x8*)(H + (size_t)s3 * 512 + c0);
#pragma unroll
    for (int j = 0; j < 8; j++)
      acc[j] += (bf2f(h0[j]) + bf2f(h1[j])) + (bf2f(h2[j]) + bf2f(h3[j]));
  }
  for (; e < end; e++) {
    int s = srcs[e];
    u16x8 hv = *(const u16x8*)(H + (size_t)s * 512 + c0);
#pragma unroll
    for (int j = 0; j < 8; j++) acc[j] += bf2f(hv[j]);
  }
  float inv = 1.0f / fmaxf((float)(end - beg), 1.0f);
  u16x8 o;
#pragma unroll
  for (int j = 0; j < 8; j++) o[j] = f2bf(acc[j] * inv);
  *(u16x8*)(Mo + (size_t)node * 512 + c0) = o;
}

// ---------------- weight cast+transpose x4 in one launch: WT[n][k] = bf16(W[k][n]) ----------------
__global__ __launch_bounds__(256) void wcast4_k(const float* __restrict__ s0, const float* __restrict__ s1,
                                                const float* __restrict__ s2, const float* __restrict__ s3,
                                                u16* __restrict__ d0, u16* __restrict__ d1,
                                                u16* __restrict__ d2, u16* __restrict__ d3) {
  const float* W = (blockIdx.z == 0) ? s0 : (blockIdx.z == 1) ? s1 : (blockIdx.z == 2) ? s2 : s3;
  u16* WT = (blockIdx.z == 0) ? d0 : (blockIdx.z == 1) ? d1 : (blockIdx.z == 2) ? d2 : d3;
  __shared__ u16 tile[64][72];
  const int k0 = blockIdx.y * 64, n0 = blockIdx.x * 64, t = threadIdx.x;
#pragma unroll
  for (int i = 0; i < 16; i++) {
    int kk = (t >> 6) * 16 + i, nn = t & 63;
    tile[nn][kk] = f2bf(W[(size_t)(k0 + kk) * 512 + n0 + nn]);
  }
  __syncthreads();
#pragma unroll
  for (int i = 0; i < 16; i++) {
    int nn = (t >> 6) * 16 + i, kk = t & 63;
    WT[(size_t)(n0 + nn) * 512 + k0 + kk] = tile[nn][kk];
  }
}

// ---------------- pooling: pooled[g] = mean rows of H2 graph block (vectorized) ----------------
__global__ __launch_bounds__(256) void pool_k(const u16* __restrict__ H2, float* __restrict__ pooled) {
  __shared__ float red[256][8];
  const int g = blockIdx.y, chunk = blockIdx.x, t = threadIdx.x;
  const int cg = t & 63, rs = t >> 6;
  const int r0 = chunk * 128;
  float a[8] = {0, 0, 0, 0, 0, 0, 0, 0};
  for (int r = r0 + rs; r < r0 + 128; r += 4) {
    u16x8 v = *(const u16x8*)(H2 + ((size_t)(g << 10) + r) * 512 + cg * 8);
#pragma unroll
    for (int j = 0; j < 8; j++) a[j] += bf2f(v[j]);
  }
#pragma unroll
  for (int j = 0; j < 8; j++) red[t][j] = a[j];
  __syncthreads();
  if (t < 64) {
#pragma unroll
    for (int j = 0; j < 8; j++) {
      float s = red[t][j] + red[t + 64][j] + red[t + 128][j] + red[t + 192][j];
      atomicAdd(&pooled[g * 512 + t * 8 + j], s * (1.0f / 1024.0f));
    }
  }
}

// ---------------- field = pooled @ gc_wr + gc_br  (fp32, tiny) ----------------
__global__ __launch_bounds__(256) void field_k(const float* __restrict__ pooled, const float* __restrict__ wr,
                                               const float* __restrict__ br, float* __restrict__ field) {
  int id = blockIdx.x * 256 + threadIdx.x;  // 32*512
  int g = id >> 9, j = id & 511;
  float s = br[j];
  for (int k = 0; k < 512; k++) s = fmaf(pooled[g * 512 + k], wr[k * 512 + j], s);
  field[id] = s;
}

// ---------------- GCN GEMM (MODE0 of round 7, unchanged discipline) ----------------
// 256x256 tile, 8 waves, BK=32, 4-buffer LDS, depth-3 counted vmcnt; XOR swizzle.
__global__ __launch_bounds__(512) void gemm0(const u16* __restrict__ A, const u16* __restrict__ BT,
                                             const float* __restrict__ bias, u16* __restrict__ C) {
  constexpr int K = 512;
  constexpr int NT = 16;
  __shared__ u16 As[4][256 * 32];
  __shared__ u16 Bs[4][256 * 32];
  const int t = threadIdx.x;
  const int wave = t >> 6, lane = t & 63;
  const int wr = wave >> 2, wc = wave & 3;
  const int lr = lane & 15, kg = lane >> 4;
  const int kx = (lr >> 1) & 3;
  const long bm0 = (long)blockIdx.y * 256;
  const int bn0 = blockIdx.x * 256;
  f32x4 acc[8][4] = {};
  const int arow = t >> 2;
  const int acs = (((t & 3) ^ ((t >> 3) & 3)) * 8);
  const u16* gA0 = A + (bm0 + arow) * K + acs;
  const u16* gA1 = gA0 + 128 * K;
  const u16* gB0 = BT + (long)(bn0 + arow) * K + acs;
  const u16* gB1 = gB0 + 128 * K;

  auto STAGE = [&](int tile) {
    const int b = tile & 3;
    const int kt = tile * 32;
    gl2lds16(gA0 + kt, &As[b][t * 8]);
    gl2lds16(gA1 + kt, &As[b][4096 + t * 8]);
    gl2lds16(gB0 + kt, &Bs[b][t * 8]);
    gl2lds16(gB1 + kt, &Bs[b][4096 + t * 8]);
  };

  STAGE(0);
  STAGE(1);
  STAGE(2);
  asm volatile("s_waitcnt vmcnt(8)" ::: "memory");
  __builtin_amdgcn_s_barrier();

#pragma unroll
  for (int tt = 0; tt < NT; ++tt) {
    const int b = tt & 3;
    if (tt + 3 < NT) STAGE(tt + 3);
    bf16x8 af[8], bfv[4];
#pragma unroll
    for (int i = 0; i < 8; i++)
      af[i] = *(const bf16x8*)&As[b][(wr * 128 + i * 16 + lr) * 32 + (kg ^ kx) * 8];
#pragma unroll
    for (int n = 0; n < 4; n++)
      bfv[n] = *(const bf16x8*)&Bs[b][(wc * 64 + n * 16 + lr) * 32 + (kg ^ kx) * 8];
#pragma unroll
    for (int i = 0; i < 8; i++)
#pragma unroll
      for (int n = 0; n < 4; n++)
        acc[i][n] = __builtin_amdgcn_mfma_f32_16x16x32_bf16(af[i], bfv[n], acc[i][n], 0, 0, 0);
    if (tt + 1 < NT) {
      const int last_staged = (tt + 3 < NT) ? (tt + 3) : (NT - 1);
      const int ahead = last_staged - (tt + 1);
      if (ahead >= 2)      asm volatile("s_waitcnt vmcnt(8)" ::: "memory");
      else if (ahead == 1) asm volatile("s_waitcnt vmcnt(4)" ::: "memory");
      else                 asm volatile("s_waitcnt vmcnt(0)" ::: "memory");
      __builtin_amdgcn_s_barrier();
    }
  }

  float bb[4];
#pragma unroll
  for (int n = 0; n < 4; n++) bb[n] = bias[bn0 + wc * 64 + n * 16 + lr];
#pragma unroll
  for (int i = 0; i < 8; i++)
#pragma unroll
    for (int n = 0; n < 4; n++) {
      int col = bn0 + wc * 64 + n * 16 + lr;
#pragma unroll
      for (int r2 = 0; r2 < 4; r2++) {
        long row = bm0 + wr * 128 + i * 16 + kg * 4 + r2;
        C[row * 512 + col] = f2bf(fmaxf(acc[i][n][r2] + bb[n], 0.0f));
      }
    }
}

// ---------------- fused query path: one block = 128 rows, whole 512-wide panel ----------------
// phase 1: z[128][512] = (relu(nodes@wt1+bt1) @ wt2 + bt2) * field[g]  -> swizzled LDS (bf16)
//   A computed in-register -> 2x8KB LDS dbuf; B frags read DIRECT from L2-resident wt2T
// phase 2: out[128][3] = relu(z @ wo1 + bo1) @ wo2 + bo2  (A from z-LDS, no barriers; B direct)
// z swizzle: u16 slot = (col>>3) ^ (row&7)  (write == read side; 2 lanes/bank on reads = free)
__global__ __launch_bounds__(512) void fused_q(const float* __restrict__ nodes3,
                                               const float* __restrict__ wt1, const float* __restrict__ bt1,
                                               const u16* __restrict__ wt2T, const float* __restrict__ bt2,
                                               const float* __restrict__ field, const u16* __restrict__ wo1T,
                                               const float* __restrict__ bo1, const float* __restrict__ wo2,
                                               const float* __restrict__ bo2, float* __restrict__ out) {
  __shared__ u16 zl[128 * 512];   // 128 KB
  __shared__ u16 Ab[2][128 * 32]; // 16 KB (aliased as epilogue reduce buffer)
  const int t = threadIdx.x;
  const int wave = t >> 6, lane = t & 63;
  const int wr = wave >> 2, wc = wave & 3;   // 2x4 wave grid; wave = 64 rows x 128 cols
  const int lr = lane & 15, kg = lane >> 4;
  const int kx = (lr >> 1) & 3;
  const long bm0 = (long)blockIdx.x * 128;
  const int g = (int)(bm0 >> 13);
  const int arow = t >> 2;
  const int acs = (((t & 3) ^ ((t >> 3) & 3)) * 8);  // Ab source-col pre-swizzle (verified scheme)
  const float nx = nodes3[(bm0 + arow) * 3 + 0];
  const float ny = nodes3[(bm0 + arow) * 3 + 1];
  const float nz = nodes3[(bm0 + arow) * 3 + 2];

  auto computeA = [&](int kt, int buf) {
    float w0[8], w1[8], w2[8], bb[8];
    const float* wp = wt1 + kt + acs;
    *(float4*)&w0[0] = *(const float4*)(wp);
    *(float4*)&w0[4] = *(const float4*)(wp + 4);
    *(float4*)&w1[0] = *(const float4*)(wp + 512);
    *(float4*)&w1[4] = *(const float4*)(wp + 516);
    *(float4*)&w2[0] = *(const float4*)(wp + 1024);
    *(float4*)&w2[4] = *(const float4*)(wp + 1028);
    *(float4*)&bb[0] = *(const float4*)(bt1 + kt + acs);
    *(float4*)&bb[4] = *(const float4*)(bt1 + kt + acs + 4);
    u16x8 o;
#pragma unroll
    for (int j = 0; j < 8; j++) {
      float v = fmaf(nx, w0[j], fmaf(ny, w1[j], fmaf(nz, w2[j], bb[j])));
      o[j] = f2bf(fmaxf(v, 0.0f));
    }
    *(u16x8*)&Ab[buf][t * 8] = o;
  };

  f32x4 acc[4][8] = {};
  bf16x8 bq[2][8];

  // ---- phase 1 ----
  computeA(0, 0);
#pragma unroll
  for (int n = 0; n < 8; n++)
    bq[0][n] = *(const bf16x8*)(wt2T + (size_t)(wc * 128 + n * 16 + lr) * 512 + kg * 8);
  __syncthreads();
#pragma unroll
  for (int tt = 0; tt < 16; ++tt) {
    const int kt = tt * 32;
    if (tt < 15) computeA(kt + 32, (tt + 1) & 1);
    bf16x8 af[4];
#pragma unroll
    for (int i = 0; i < 4; i++)
      af[i] = *(const bf16x8*)&Ab[tt & 1][(wr * 64 + i * 16 + lr) * 32 + (kg ^ kx) * 8];
    if (tt < 15) {
#pragma unroll
      for (int n = 0; n < 8; n++)
        bq[(tt + 1) & 1][n] =
            *(const bf16x8*)(wt2T + (size_t)(wc * 128 + n * 16 + lr) * 512 + kt + 32 + kg * 8);
    }
#pragma unroll
    for (int i = 0; i < 4; i++)
#pragma unroll
      for (int n = 0; n < 8; n++)
        acc[i][n] = __builtin_amdgcn_mfma_f32_16x16x32_bf16(af[i], bq[tt & 1][n], acc[i][n], 0, 0, 0);
    __syncthreads();
  }

  // z = (acc + bt2) * field -> swizzled LDS
  {
    float bb2[8], fmv[8];
#pragma unroll
    for (int n = 0; n < 8; n++) {
      int col = wc * 128 + n * 16 + lr;
      bb2[n] = bt2[col];
      fmv[n] = field[g * 512 + col];
    }
#pragma unroll
    for (int i = 0; i < 4; i++)
#pragma unroll
      for (int n = 0; n < 8; n++) {
        int col = wc * 128 + n * 16 + lr;
#pragma unroll
        for (int r2 = 0; r2 < 4; r2++) {
          int row = wr * 64 + i * 16 + kg * 4 + r2;
          int slot = (col >> 3) ^ (row & 7);
          zl[row * 512 + slot * 8 + (col & 7)] = f2bf((acc[i][n][r2] + bb2[n]) * fmv[n]);
        }
      }
  }
  __syncthreads();

  // ---- phase 2 (no barriers: zl is read-only) ----
  f32x4 ac2[4][8] = {};
#pragma unroll
  for (int n = 0; n < 8; n++)
    bq[0][n] = *(const bf16x8*)(wo1T + (size_t)(wc * 128 + n * 16 + lr) * 512 + kg * 8);
#pragma unroll
  for (int tt = 0; tt < 16; ++tt) {
    const int kt = tt * 32;
    bf16x8 af[4];
#pragma unroll
    for (int i = 0; i < 4; i++) {
      int row = wr * 64 + i * 16 + lr;
      int slot = ((kt >> 3) + kg) ^ (lr & 7);
      af[i] = *(const bf16x8*)&zl[row * 512 + slot * 8];
    }
    if (tt < 15) {
#pragma unroll
      for (int n = 0; n < 8; n++)
        bq[(tt + 1) & 1][n] =
            *(const bf16x8*)(wo1T + (size_t)(wc * 128 + n * 16 + lr) * 512 + kt + 32 + kg * 8);
    }
#pragma unroll
    for (int i = 0; i < 4; i++)
#pragma unroll
      for (int n = 0; n < 8; n++)
        ac2[i][n] = __builtin_amdgcn_mfma_f32_16x16x32_bf16(af[i], bq[tt & 1][n], ac2[i][n], 0, 0, 0);
  }

  // epilogue: z2 = relu(ac2 + bo1); out = z2 @ wo2 + bo2 (shfl over lr, LDS over wc)
  __syncthreads();  // all zl reads done; Ab reusable as reduce buffer
  float* red = (float*)&Ab[0][0];  // [8 waves][64 rows][3]
#pragma unroll
  for (int i = 0; i < 4; i++) {
    float po[4][3] = {};
#pragma unroll
    for (int n = 0; n < 8; n++) {
      int col = wc * 128 + n * 16 + lr;
      float b3 = bo1[col];
      float wa = wo2[col * 3 + 0], wb = wo2[col * 3 + 1], wv = wo2[col * 3 + 2];
#pragma unroll
      for (int r2 = 0; r2 < 4; r2++) {
        float v = fmaxf(ac2[i][n][r2] + b3, 0.0f);
        po[r2][0] = fmaf(v, wa, po[r2][0]);
        po[r2][1] = fmaf(v, wb, po[r2][1]);
        po[r2][2] = fmaf(v, wv, po[r2][2]);
      }
    }
#pragma unroll
    for (int s = 1; s < 16; s <<= 1)
#pragma unroll
      for (int r2 = 0; r2 < 4; r2++)
#pragma unroll
        for (int o = 0; o < 3; o++) po[r2][o] += __shfl_xor(po[r2][o], s, 64);
    if (lr == 0) {
#pragma unroll
      for (int r2 = 0; r2 < 4; r2++) {
        int rrow = i * 16 + kg * 4 + r2;
#pragma unroll
        for (int o = 0; o < 3; o++) red[(wave * 64 + rrow) * 3 + o] = po[r2][o];
      }
    }
  }
  __syncthreads();
  if (t < 384) {
    int row = t / 3, o = t - row * 3;
    int wrr = row >> 6, rrow = row & 63;
    float s = bo2[o];
#pragma unroll
    for (int w = 0; w < 4; w++) s += red[((wrr * 4 + w) * 64 + rrow) * 3 + o];
    out[(bm0 + row) * 3 + o] = s;
  }
}

extern "C" void kernel_launch(void* const* d_in, const int* in_sizes, int n_in,
                              void* d_out, int out_size, void* d_ws, size_t ws_size,
                              hipStream_t stream) {
  const float* known = (const float*)d_in[0];
  const float* nodes = (const float*)d_in[1];
  const int* esrc = (const int*)d_in[2];
  const int* edst = (const int*)d_in[3];
  const float* gc_w0 = (const float*)d_in[6];
  const float* gc_b0 = (const float*)d_in[7];
  const float* gc_w1 = (const float*)d_in[8];
  const float* gc_b1 = (const float*)d_in[9];
  const float* gc_w2 = (const float*)d_in[10];
  const float* gc_b2 = (const float*)d_in[11];
  const float* gc_wr = (const float*)d_in[12];
  const float* gc_br = (const float*)d_in[13];
  const float* wt1 = (const float*)d_in[14];
  const float* bt1 = (const float*)d_in[15];
  const float* wt2 = (const float*)d_in[16];
  const float* bt2 = (const float*)d_in[17];
  const float* wo1 = (const float*)d_in[18];
  const float* bo1 = (const float*)d_in[19];
  const float* wo2 = (const float*)d_in[20];
  const float* bo2 = (const float*)d_in[21];
  float* out = (float*)d_out;
  (void)in_sizes; (void)n_in; (void)out_size; (void)ws_size;

  char* ws = (char*)d_ws;
  size_t off_b = 0;
  auto alloc = [&](size_t n) -> void* {
    void* p = ws + off_b;
    off_b += (n + 255) & ~(size_t)255;
    return p;
  };
  u16* w1T  = (u16*)alloc(512 * 512 * 2);
  u16* w2T  = (u16*)alloc(512 * 512 * 2);
  u16* wt2T = (u16*)alloc(512 * 512 * 2);
  u16* wo1T = (u16*)alloc(512 * 512 * 2);
  int* cnt   = (int*)alloc(NKVAL * 4);
  int* off   = (int*)alloc((NKVAL + 1) * 4);
  int* cur   = (int*)alloc(NKVAL * 4);
  int* srcs  = (int*)alloc((size_t)EVAL * 4);
  float* m0     = (float*)alloc(NKVAL * 3 * 4);
  float* pooled = (float*)alloc(32 * 512 * 4);
  float* field  = (float*)alloc(32 * 512 * 4);
  u16* bufA = (u16*)alloc((size_t)NKVAL * 512 * 2);
  u16* bufB = (u16*)alloc((size_t)NKVAL * 512 * 2);
  u16* bufC = (u16*)alloc((size_t)NKVAL * 512 * 2);

  hipMemsetAsync(cnt, 0, NKVAL * 4, stream);
  hipMemsetAsync(cur, 0, NKVAL * 4, stream);
  hipMemsetAsync(pooled, 0, 32 * 512 * 4, stream);

  wcast4_k<<<dim3(8, 8, 4), 256, 0, stream>>>(gc_w1, gc_w2, wt2, wo1, w1T, w2T, wt2T, wo1T);

  degcnt_k<<<EVAL / 256, 256, 0, stream>>>(edst, cnt);
  scan_k<<<1, 1024, 0, stream>>>(cnt, off);
  scatter_k<<<EVAL / 256, 256, 0, stream>>>(esrc, edst, off, cur, srcs);
  agg0_csr<<<NKVAL / 256, 256, 0, stream>>>(off, srcs, known, m0);

  // h0 = relu((m0/deg) @ gc_w0 + b0)
  k3_dense<<<NKVAL * 64 / 256, 256, 0, stream>>>(m0, cnt, gc_w0, gc_b0, bufA, NKVAL);
  // m1 = segsum(h0[src])/deg
  agg_csr<<<NKVAL / 4, 256, 0, stream>>>(bufA, off, srcs, bufB);
  // h1 = relu(m1 @ W1 + b1)
  gemm0<<<dim3(2, NKVAL / 256), 512, 0, stream>>>(bufB, w1T, gc_b1, bufC);
  // m2
  agg_csr<<<NKVAL / 4, 256, 0, stream>>>(bufC, off, srcs, bufA);
  // h2
  gemm0<<<dim3(2, NKVAL / 256), 512, 0, stream>>>(bufA, w2T, gc_b2, bufB);
  pool_k<<<dim3(8, 32), 256, 0, stream>>>(bufB, pooled);
  field_k<<<64, 256, 0, stream>>>(pooled, gc_wr, gc_br, field);

  // whole query path in one kernel: out = relu(((relu(nodes@wt1+bt1)@wt2+bt2)*field)@wo1+bo1)@wo2+bo2
  fused_q<<<NQVAL / 128, 512, 0, stream>>>(nodes, wt1, bt1, wt2T, bt2, field, wo1T, bo1, wo2, bo2, out);
}

// Round 9
// 582.451 us; speedup vs baseline: 1.4250x; 1.4250x over previous
//
#include <hip/hip_runtime.h>

typedef unsigned short u16;
using u16x8  = __attribute__((ext_vector_type(8))) unsigned short;
using bf16x8 = __attribute__((ext_vector_type(8))) __bf16;
using f32x4  = __attribute__((ext_vector_type(4))) float;

#define NKVAL 32768
#define NQVAL 262144
#define EVAL  524288

__device__ __forceinline__ u16 f2bf(float f) {
  unsigned u = __float_as_uint(f);
  u = (u + 0x7fffu + ((u >> 16) & 1u)) >> 16;   // RNE
  return (u16)u;
}
__device__ __forceinline__ float bf2f(u16 h) {
  return __uint_as_float(((unsigned)h) << 16);
}
__device__ __forceinline__ void gl2lds16(const u16* g, u16* l) {
  __builtin_amdgcn_global_load_lds((const __attribute__((address_space(1))) void*)g,
                                   (__attribute__((address_space(3))) void*)l, 16, 0, 0);
}

// ---------------- int degree ----------------
__global__ __launch_bounds__(256) void degcnt_k(const int* __restrict__ dst, int* __restrict__ cnt) {
  int e = blockIdx.x * 256 + threadIdx.x;
  if (e < EVAL) atomicAdd(&cnt[dst[e]], 1);
}

// ---------------- exclusive scan over cnt[NKVAL] -> off[NKVAL+1], single block ----------------
__global__ __launch_bounds__(1024) void scan_k(const int* __restrict__ cnt, int* __restrict__ off) {
  __shared__ int part[1024];
  const int t = threadIdx.x;
  const int base = t * 32;
  int local[32];
  int s = 0;
#pragma unroll
  for (int i = 0; i < 32; i++) { local[i] = s; s += cnt[base + i]; }
  part[t] = s;
  __syncthreads();
  for (int d = 1; d < 1024; d <<= 1) {
    int v = (t >= d) ? part[t - d] : 0;
    __syncthreads();
    part[t] += v;
    __syncthreads();
  }
  int pre = (t == 0) ? 0 : part[t - 1];
#pragma unroll
  for (int i = 0; i < 32; i++) off[base + i] = pre + local[i];
  if (t == 1023) off[NKVAL] = pre + s;
}

// ---------------- scatter edges into CSR-by-dst ----------------
__global__ __launch_bounds__(256) void scatter_k(const int* __restrict__ src, const int* __restrict__ dst,
                                                 const int* __restrict__ off, int* __restrict__ cur,
                                                 int* __restrict__ srcs_sorted) {
  int e = blockIdx.x * 256 + threadIdx.x;
  if (e < EVAL) {
    int d = dst[e];
    int p = atomicAdd(&cur[d], 1);
    srcs_sorted[off[d] + p] = src[e];
  }
}

// ---------------- layer-0 aggregation via CSR (no atomics) ----------------
__global__ __launch_bounds__(256) void agg0_csr(const int* __restrict__ off, const int* __restrict__ srcs,
                                                const float* __restrict__ known, float* __restrict__ m0) {
  int d = blockIdx.x * 256 + threadIdx.x;
  if (d >= NKVAL) return;
  int b = off[d], e = off[d + 1];
  float a0 = 0.f, a1 = 0.f, a2 = 0.f;
  for (int i = b; i < e; i++) {
    int s = srcs[i];
    a0 += known[s * 3 + 0];
    a1 += known[s * 3 + 1];
    a2 += known[s * 3 + 2];
  }
  m0[d * 3 + 0] = a0;
  m0[d * 3 + 1] = a1;
  m0[d * 3 + 2] = a2;
}

// ---------------- K=3 dense: Y = relu((X[/cnt]) @ W[3,512] + b) -> bf16, vectorized ----------------
__global__ __launch_bounds__(256) void k3_dense(const float* __restrict__ X, const int* __restrict__ cnt,
                                                const float* __restrict__ W, const float* __restrict__ Bb,
                                                u16* __restrict__ Y, int M) {
  int id = blockIdx.x * 256 + threadIdx.x;  // M*64 threads, 8 outputs each
  if (id >= M * 64) return;
  int i = id >> 6, j0 = (id & 63) * 8;
  float x0 = X[i * 3 + 0], x1 = X[i * 3 + 1], x2 = X[i * 3 + 2];
  if (cnt) {
    float inv = 1.0f / fmaxf((float)cnt[i], 1.0f);
    x0 *= inv; x1 *= inv; x2 *= inv;
  }
  u16x8 o;
#pragma unroll
  for (int j = 0; j < 8; j++) {
    float v = fmaf(x0, W[j0 + j], Bb[j0 + j]);
    v = fmaf(x1, W[512 + j0 + j], v);
    v = fmaf(x2, W[1024 + j0 + j], v);
    o[j] = f2bf(fmaxf(v, 0.0f));
  }
  *(u16x8*)(Y + (size_t)i * 512 + j0) = o;
}

// ---------------- GCN aggregation via CSR: wave per dst node, regs only ----------------
__global__ __launch_bounds__(256) void agg_csr(const u16* __restrict__ H, const int* __restrict__ off,
                                               const int* __restrict__ srcs, u16* __restrict__ Mo) {
  const int raw = blockIdx.x;
  const int nb = (raw & 7) * 1024 + (raw >> 3);
  const int node = nb * 4 + (threadIdx.x >> 6);
  const int lane = threadIdx.x & 63;
  const int beg = off[node], end = off[node + 1];
  const int c0 = lane * 8;
  float acc[8] = {0, 0, 0, 0, 0, 0, 0, 0};
  int e = beg;
  for (; e + 4 <= end; e += 4) {
    int s0 = srcs[e], s1 = srcs[e + 1], s2 = srcs[e + 2], s3 = srcs[e + 3];
    u16x8 h0 = *(const u16x8*)(H + (size_t)s0 * 512 + c0);
    u16x8 h1 = *(const u16x8*)(H + (size_t)s1 * 512 + c0);
    u16x8 h2 = *(const u16x8*)(H + (size_t)s2 * 512 + c0);
    u16x8 h3 = *(const u16x8*)(H + (size_t)s3 * 512 + c0);
#pragma unroll
    for (int j = 0; j < 8; j++)
      acc[j] += (bf2f(h0[j]) + bf2f(h1[j])) + (bf2f(h2[j]) + bf2f(h3[j]));
  }
  for (; e < end; e++) {
    int s = srcs[e];
    u16x8 hv = *(const u16x8*)(H + (size_t)s * 512 + c0);
#pragma unroll
    for (int j = 0; j < 8; j++) acc[j] += bf2f(hv[j]);
  }
  float inv = 1.0f / fmaxf((float)(end - beg), 1.0f);
  u16x8 o;
#pragma unroll
  for (int j = 0; j < 8; j++) o[j] = f2bf(acc[j] * inv);
  *(u16x8*)(Mo + (size_t)node * 512 + c0) = o;
}

// ---------------- weight cast+transpose x2: WT[n][k] = bf16(W[k][n]) ----------------
__global__ __launch_bounds__(256) void wcast2_k(const float* __restrict__ s0, const float* __restrict__ s1,
                                                u16* __restrict__ d0, u16* __restrict__ d1) {
  const float* W = (blockIdx.z == 0) ? s0 : s1;
  u16* WT = (blockIdx.z == 0) ? d0 : d1;
  __shared__ u16 tile[64][72];
  const int k0 = blockIdx.y * 64, n0 = blockIdx.x * 64, t = threadIdx.x;
#pragma unroll
  for (int i = 0; i < 16; i++) {
    int kk = (t >> 6) * 16 + i, nn = t & 63;
    tile[nn][kk] = f2bf(W[(size_t)(k0 + kk) * 512 + n0 + nn]);
  }
  __syncthreads();
#pragma unroll
  for (int i = 0; i < 16; i++) {
    int nn = (t >> 6) * 16 + i, kk = t & 63;
    WT[(size_t)(n0 + nn) * 512 + k0 + kk] = tile[nn][kk];
  }
}

// ---------------- fragment-major B pack: F[kblk][nblk][lane][8] = bf16(W[k][n]) ----------------
// k = kblk*32 + (lane>>4)*8 + j ; n = nblk*16 + (lane&15). One thread per (kblk,nblk,lane).
__global__ __launch_bounds__(256) void wfrag_k(const float* __restrict__ W, u16* __restrict__ F) {
  int id = blockIdx.x * 256 + threadIdx.x;   // 16*32*64 = 32768
  int lane = id & 63, nblk = (id >> 6) & 31, kblk = id >> 11;
  int k0 = kblk * 32 + (lane >> 4) * 8;
  int n = nblk * 16 + (lane & 15);
  u16x8 o;
#pragma unroll
  for (int j = 0; j < 8; j++) o[j] = f2bf(W[(size_t)(k0 + j) * 512 + n]);
  *(u16x8*)(F + (size_t)id * 8) = o;
}

// ---------------- pooling: pooled[g] = mean rows of H2 graph block (vectorized) ----------------
__global__ __launch_bounds__(256) void pool_k(const u16* __restrict__ H2, float* __restrict__ pooled) {
  __shared__ float red[256][8];
  const int g = blockIdx.y, chunk = blockIdx.x, t = threadIdx.x;
  const int cg = t & 63, rs = t >> 6;
  const int r0 = chunk * 128;
  float a[8] = {0, 0, 0, 0, 0, 0, 0, 0};
  for (int r = r0 + rs; r < r0 + 128; r += 4) {
    u16x8 v = *(const u16x8*)(H2 + ((size_t)(g << 10) + r) * 512 + cg * 8);
#pragma unroll
    for (int j = 0; j < 8; j++) a[j] += bf2f(v[j]);
  }
#pragma unroll
  for (int j = 0; j < 8; j++) red[t][j] = a[j];
  __syncthreads();
  if (t < 64) {
#pragma unroll
    for (int j = 0; j < 8; j++) {
      float s = red[t][j] + red[t + 64][j] + red[t + 128][j] + red[t + 192][j];
      atomicAdd(&pooled[g * 512 + t * 8 + j], s * (1.0f / 1024.0f));
    }
  }
}

// ---------------- field = pooled @ gc_wr + gc_br  (fp32, tiny) ----------------
__global__ __launch_bounds__(256) void field_k(const float* __restrict__ pooled, const float* __restrict__ wr,
                                               const float* __restrict__ br, float* __restrict__ field) {
  int id = blockIdx.x * 256 + threadIdx.x;  // 32*512
  int g = id >> 9, j = id & 511;
  float s = br[j];
  for (int k = 0; k < 512; k++) s = fmaf(pooled[g * 512 + k], wr[k * 512 + j], s);
  field[id] = s;
}

// ---------------- GCN GEMM: 256x256 tile, 4-buffer, depth-3 counted vmcnt, XOR swizzle ----------------
__global__ __launch_bounds__(512) void gemm0(const u16* __restrict__ A, const u16* __restrict__ BT,
                                             const float* __restrict__ bias, u16* __restrict__ C) {
  constexpr int K = 512;
  constexpr int NT = 16;
  __shared__ u16 As[4][256 * 32];
  __shared__ u16 Bs[4][256 * 32];
  const int t = threadIdx.x;
  const int wave = t >> 6, lane = t & 63;
  const int wr = wave >> 2, wc = wave & 3;
  const int lr = lane & 15, kg = lane >> 4;
  const int kx = (lr >> 1) & 3;
  const long bm0 = (long)blockIdx.y * 256;
  const int bn0 = blockIdx.x * 256;
  f32x4 acc[8][4] = {};
  const int arow = t >> 2;
  const int acs = (((t & 3) ^ ((t >> 3) & 3)) * 8);
  const u16* gA0 = A + (bm0 + arow) * K + acs;
  const u16* gA1 = gA0 + 128 * K;
  const u16* gB0 = BT + (long)(bn0 + arow) * K + acs;
  const u16* gB1 = gB0 + 128 * K;

  auto STAGE = [&](int tile) {
    const int b = tile & 3;
    const int kt = tile * 32;
    gl2lds16(gA0 + kt, &As[b][t * 8]);
    gl2lds16(gA1 + kt, &As[b][4096 + t * 8]);
    gl2lds16(gB0 + kt, &Bs[b][t * 8]);
    gl2lds16(gB1 + kt, &Bs[b][4096 + t * 8]);
  };

  STAGE(0);
  STAGE(1);
  STAGE(2);
  asm volatile("s_waitcnt vmcnt(8)" ::: "memory");
  __builtin_amdgcn_s_barrier();

#pragma unroll
  for (int tt = 0; tt < NT; ++tt) {
    const int b = tt & 3;
    if (tt + 3 < NT) STAGE(tt + 3);
    bf16x8 af[8], bfv[4];
#pragma unroll
    for (int i = 0; i < 8; i++)
      af[i] = *(const bf16x8*)&As[b][(wr * 128 + i * 16 + lr) * 32 + (kg ^ kx) * 8];
#pragma unroll
    for (int n = 0; n < 4; n++)
      bfv[n] = *(const bf16x8*)&Bs[b][(wc * 64 + n * 16 + lr) * 32 + (kg ^ kx) * 8];
#pragma unroll
    for (int i = 0; i < 8; i++)
#pragma unroll
      for (int n = 0; n < 4; n++)
        acc[i][n] = __builtin_amdgcn_mfma_f32_16x16x32_bf16(af[i], bfv[n], acc[i][n], 0, 0, 0);
    if (tt + 1 < NT) {
      const int last_staged = (tt + 3 < NT) ? (tt + 3) : (NT - 1);
      const int ahead = last_staged - (tt + 1);
      if (ahead >= 2)      asm volatile("s_waitcnt vmcnt(8)" ::: "memory");
      else if (ahead == 1) asm volatile("s_waitcnt vmcnt(4)" ::: "memory");
      else                 asm volatile("s_waitcnt vmcnt(0)" ::: "memory");
      __builtin_amdgcn_s_barrier();
    }
  }

  float bb[4];
#pragma unroll
  for (int n = 0; n < 4; n++) bb[n] = bias[bn0 + wc * 64 + n * 16 + lr];
#pragma unroll
  for (int i = 0; i < 8; i++)
#pragma unroll
    for (int n = 0; n < 4; n++) {
      int col = bn0 + wc * 64 + n * 16 + lr;
#pragma unroll
      for (int r2 = 0; r2 < 4; r2++) {
        long row = bm0 + wr * 128 + i * 16 + kg * 4 + r2;
        C[row * 512 + col] = f2bf(fmaxf(acc[i][n][r2] + bb[n], 0.0f));
      }
    }
}

// ---------------- fused query path (fixed addressing) ----------------
// phase 1: z = (relu(nodes@wt1+bt1) @ wt2 + bt2) * field  -> z LDS in [16 kblk][128 row][32] subtiles
//          (same layout class as gemm0 As: 64B row stride + kg^kx slot XOR = measured 0-conflict)
// phase 2: out = relu(z @ wo1 + bo1) @ wo2 + bo2, A-frags from z LDS, barrier-free
// B operands come from FRAGMENT-MAJOR packs (wt2F/wo1F): per step each wave loads 8 contiguous
// 1KB fragment tiles (fully coalesced; fixes the 1024B-stride gather = 4x L2 waste of round 8).
__global__ __launch_bounds__(512, 1) void fused_q(const float* __restrict__ nodes3,
                                                  const float* __restrict__ wt1, const float* __restrict__ bt1,
                                                  const u16* __restrict__ wt2F, const float* __restrict__ bt2,
                                                  const float* __restrict__ field, const u16* __restrict__ wo1F,
                                                  const float* __restrict__ bo1, const float* __restrict__ wo2,
                                                  const float* __restrict__ bo2, float* __restrict__ out) {
  __shared__ u16 zl[16][128 * 32];  // 128 KB, subtiled
  __shared__ u16 Ab[2][128 * 32];   // 16 KB dbuf (aliased as epilogue reduce buffer)
  const int t = threadIdx.x;
  const int wave = t >> 6, lane = t & 63;
  const int wr = wave >> 2, wc = wave & 3;   // 2x4 wave grid; wave = 64 rows x 128 cols
  const int lr = lane & 15, kg = lane >> 4;
  const int kx = (lr >> 1) & 3;
  const long bm0 = (long)blockIdx.x * 128;
  const int g = (int)(bm0 >> 13);
  const int arow = t >> 2;
  const int acs = (((t & 3) ^ ((t >> 3) & 3)) * 8);  // Ab source-col pre-swizzle (verified)
  const float nx = nodes3[(bm0 + arow) * 3 + 0];
  const float ny = nodes3[(bm0 + arow) * 3 + 1];
  const float nz = nodes3[(bm0 + arow) * 3 + 2];

  auto computeA = [&](int kt, int buf) {
    float w0[8], w1[8], w2[8], bb[8];
    const float* wp = wt1 + kt + acs;
    *(float4*)&w0[0] = *(const float4*)(wp);
    *(float4*)&w0[4] = *(const float4*)(wp + 4);
    *(float4*)&w1[0] = *(const float4*)(wp + 512);
    *(float4*)&w1[4] = *(const float4*)(wp + 516);
    *(float4*)&w2[0] = *(const float4*)(wp + 1024);
    *(float4*)&w2[4] = *(const float4*)(wp + 1028);
    *(float4*)&bb[0] = *(const float4*)(bt1 + kt + acs);
    *(float4*)&bb[4] = *(const float4*)(bt1 + kt + acs + 4);
    u16x8 o;
#pragma unroll
    for (int j = 0; j < 8; j++) {
      float v = fmaf(nx, w0[j], fmaf(ny, w1[j], fmaf(nz, w2[j], bb[j])));
      o[j] = f2bf(fmaxf(v, 0.0f));
    }
    *(u16x8*)&Ab[buf][t * 8] = o;
  };

  f32x4 acc[4][8] = {};
  bf16x8 bq[2][8];

  // ---- phase 1 ----
  computeA(0, 0);
#pragma unroll
  for (int n = 0; n < 8; n++)
    bq[0][n] = *(const bf16x8*)(wt2F + ((size_t)((0 * 32 + wc * 8 + n) * 64 + lane)) * 8);
  __syncthreads();
#pragma unroll
  for (int tt = 0; tt < 16; ++tt) {
    if (tt < 15) computeA((tt + 1) * 32, (tt + 1) & 1);
    bf16x8 af[4];
#pragma unroll
    for (int i = 0; i < 4; i++)
      af[i] = *(const bf16x8*)&Ab[tt & 1][(wr * 64 + i * 16 + lr) * 32 + (kg ^ kx) * 8];
    if (tt < 15) {
#pragma unroll
      for (int n = 0; n < 8; n++)
        bq[(tt + 1) & 1][n] =
            *(const bf16x8*)(wt2F + ((size_t)(((tt + 1) * 32 + wc * 8 + n) * 64 + lane)) * 8);
    }
#pragma unroll
    for (int i = 0; i < 4; i++)
#pragma unroll
      for (int n = 0; n < 8; n++)
        acc[i][n] = __builtin_amdgcn_mfma_f32_16x16x32_bf16(af[i], bq[tt & 1][n], acc[i][n], 0, 0, 0);
    __syncthreads();
  }

  // z = (acc + bt2) * field -> subtiled, swizzled LDS
  {
    float bb2[8], fmv[8];
#pragma unroll
    for (int n = 0; n < 8; n++) {
      int col = wc * 128 + n * 16 + lr;
      bb2[n] = bt2[col];
      fmv[n] = field[g * 512 + col];
    }
#pragma unroll
    for (int i = 0; i < 4; i++)
#pragma unroll
      for (int n = 0; n < 8; n++) {
        int c32 = (n & 1) * 16 + lr;         // col within 32-block
        int kblk = wc * 4 + (n >> 1);        // which 32-col block
#pragma unroll
        for (int r2 = 0; r2 < 4; r2++) {
          int row = wr * 64 + i * 16 + kg * 4 + r2;
          int slot = (c32 >> 3) ^ ((row >> 1) & 3);
          zl[kblk][row * 32 + slot * 8 + (c32 & 7)] = f2bf((acc[i][n][r2] + bb2[n]) * fmv[n]);
        }
      }
  }
  __syncthreads();

  // ---- phase 2 (no barriers: zl read-only) ----
  f32x4 ac2[4][8] = {};
#pragma unroll
  for (int n = 0; n < 8; n++)
    bq[0][n] = *(const bf16x8*)(wo1F + ((size_t)((0 * 32 + wc * 8 + n) * 64 + lane)) * 8);
#pragma unroll
  for (int tt = 0; tt < 16; ++tt) {
    bf16x8 af[4];
#pragma unroll
    for (int i = 0; i < 4; i++)
      af[i] = *(const bf16x8*)&zl[tt][(wr * 64 + i * 16 + lr) * 32 + (kg ^ kx) * 8];
    if (tt < 15) {
#pragma unroll
      for (int n = 0; n < 8; n++)
        bq[(tt + 1) & 1][n] =
            *(const bf16x8*)(wo1F + ((size_t)(((tt + 1) * 32 + wc * 8 + n) * 64 + lane)) * 8);
    }
#pragma unroll
    for (int i = 0; i < 4; i++)
#pragma unroll
      for (int n = 0; n < 8; n++)
        ac2[i][n] = __builtin_amdgcn_mfma_f32_16x16x32_bf16(af[i], bq[tt & 1][n], ac2[i][n], 0, 0, 0);
  }

  // epilogue: z2 = relu(ac2 + bo1); out = z2 @ wo2 + bo2 (shfl over lr, LDS over waves)
  __syncthreads();
  float* red = (float*)&Ab[0][0];  // [8 waves][64 rows][3] = 6KB
#pragma unroll
  for (int i = 0; i < 4; i++) {
    float po[4][3] = {};
#pragma unroll
    for (int n = 0; n < 8; n++) {
      int col = wc * 128 + n * 16 + lr;
      float b3 = bo1[col];
      float wa = wo2[col * 3 + 0], wb = wo2[col * 3 + 1], wv = wo2[col * 3 + 2];
#pragma unroll
      for (int r2 = 0; r2 < 4; r2++) {
        float v = fmaxf(ac2[i][n][r2] + b3, 0.0f);
        po[r2][0] = fmaf(v, wa, po[r2][0]);
        po[r2][1] = fmaf(v, wb, po[r2][1]);
        po[r2][2] = fmaf(v, wv, po[r2][2]);
      }
    }
#pragma unroll
    for (int s = 1; s < 16; s <<= 1)
#pragma unroll
      for (int r2 = 0; r2 < 4; r2++)
#pragma unroll
        for (int o = 0; o < 3; o++) po[r2][o] += __shfl_xor(po[r2][o], s, 64);
    if (lr == 0) {
#pragma unroll
      for (int r2 = 0; r2 < 4; r2++) {
        int rrow = i * 16 + kg * 4 + r2;
#pragma unroll
        for (int o = 0; o < 3; o++) red[(wave * 64 + rrow) * 3 + o] = po[r2][o];
      }
    }
  }
  __syncthreads();
  if (t < 384) {
    int row = t / 3, o = t - row * 3;
    int wrr = row >> 6, rrow = row & 63;
    float s = bo2[o];
#pragma unroll
    for (int w = 0; w < 4; w++) s += red[((wrr * 4 + w) * 64 + rrow) * 3 + o];
    out[(bm0 + row) * 3 + o] = s;
  }
}

extern "C" void kernel_launch(void* const* d_in, const int* in_sizes, int n_in,
                              void* d_out, int out_size, void* d_ws, size_t ws_size,
                              hipStream_t stream) {
  const float* known = (const float*)d_in[0];
  const float* nodes = (const float*)d_in[1];
  const int* esrc = (const int*)d_in[2];
  const int* edst = (const int*)d_in[3];
  const float* gc_w0 = (const float*)d_in[6];
  const float* gc_b0 = (const float*)d_in[7];
  const float* gc_w1 = (const float*)d_in[8];
  const float* gc_b1 = (const float*)d_in[9];
  const float* gc_w2 = (const float*)d_in[10];
  const float* gc_b2 = (const float*)d_in[11];
  const float* gc_wr = (const float*)d_in[12];
  const float* gc_br = (const float*)d_in[13];
  const float* wt1 = (const float*)d_in[14];
  const float* bt1 = (const float*)d_in[15];
  const float* wt2 = (const float*)d_in[16];
  const float* bt2 = (const float*)d_in[17];
  const float* wo1 = (const float*)d_in[18];
  const float* bo1 = (const float*)d_in[19];
  const float* wo2 = (const float*)d_in[20];
  const float* bo2 = (const float*)d_in[21];
  float* out = (float*)d_out;
  (void)in_sizes; (void)n_in; (void)out_size; (void)ws_size;

  char* ws = (char*)d_ws;
  size_t off_b = 0;
  auto alloc = [&](size_t n) -> void* {
    void* p = ws + off_b;
    off_b += (n + 255) & ~(size_t)255;
    return p;
  };
  u16* w1T   = (u16*)alloc(512 * 512 * 2);
  u16* w2T   = (u16*)alloc(512 * 512 * 2);
  u16* wt2F  = (u16*)alloc(512 * 512 * 2);
  u16* wo1F  = (u16*)alloc(512 * 512 * 2);
  int* cnt   = (int*)alloc(NKVAL * 4);
  int* off   = (int*)alloc((NKVAL + 1) * 4);
  int* cur   = (int*)alloc(NKVAL * 4);
  int* srcs  = (int*)alloc((size_t)EVAL * 4);
  float* m0     = (float*)alloc(NKVAL * 3 * 4);
  float* pooled = (float*)alloc(32 * 512 * 4);
  float* field  = (float*)alloc(32 * 512 * 4);
  u16* bufA = (u16*)alloc((size_t)NKVAL * 512 * 2);
  u16* bufB = (u16*)alloc((size_t)NKVAL * 512 * 2);
  u16* bufC = (u16*)alloc((size_t)NKVAL * 512 * 2);

  hipMemsetAsync(cnt, 0, NKVAL * 4, stream);
  hipMemsetAsync(cur, 0, NKVAL * 4, stream);
  hipMemsetAsync(pooled, 0, 32 * 512 * 4, stream);

  wcast2_k<<<dim3(8, 8, 2), 256, 0, stream>>>(gc_w1, gc_w2, w1T, w2T);
  wfrag_k<<<128, 256, 0, stream>>>(wt2, wt2F);
  wfrag_k<<<128, 256, 0, stream>>>(wo1, wo1F);

  degcnt_k<<<EVAL / 256, 256, 0, stream>>>(edst, cnt);
  scan_k<<<1, 1024, 0, stream>>>(cnt, off);
  scatter_k<<<EVAL / 256, 256, 0, stream>>>(esrc, edst, off, cur, srcs);
  agg0_csr<<<NKVAL / 256, 256, 0, stream>>>(off, srcs, known, m0);

  // h0 = relu((m0/deg) @ gc_w0 + b0)
  k3_dense<<<NKVAL * 64 / 256, 256, 0, stream>>>(m0, cnt, gc_w0, gc_b0, bufA, NKVAL);
  // m1 = segsum(h0[src])/deg
  agg_csr<<<NKVAL / 4, 256, 0, stream>>>(bufA, off, srcs, bufB);
  // h1 = relu(m1 @ W1 + b1)
  gemm0<<<dim3(2, NKVAL / 256), 512, 0, stream>>>(bufB, w1T, gc_b1, bufC);
  // m2
  agg_csr<<<NKVAL / 4, 256, 0, stream>>>(bufC, off, srcs, bufA);
  // h2
  gemm0<<<dim3(2, NKVAL / 256), 512, 0, stream>>>(bufA, w2T, gc_b2, bufB);
  pool_k<<<dim3(8, 32), 256, 0, stream>>>(bufB, pooled);
  field_k<<<64, 256, 0, stream>>>(pooled, gc_wr, gc_br, field);

  // whole query path in one kernel
  fused_q<<<NQVAL / 128, 512, 0, stream>>>(nodes, wt1, bt1, wt2F, bt2, field, wo1F, bo1, wo2, bo2, out);
}

// Round 10
// 564.599 us; speedup vs baseline: 1.4701x; 1.0316x over previous
//
#include <hip/hip_runtime.h>

typedef unsigned short u16;
using u16x8  = __attribute__((ext_vector_type(8))) unsigned short;
using bf16x8 = __attribute__((ext_vector_type(8))) __bf16;
using f32x4  = __attribute__((ext_vector_type(4))) float;

#define NKVAL 32768
#define NQVAL 262144
#define EVAL  524288

__device__ __forceinline__ u16 f2bf(float f) {
  unsigned u = __float_as_uint(f);
  u = (u + 0x7fffu + ((u >> 16) & 1u)) >> 16;   // RNE
  return (u16)u;
}
__device__ __forceinline__ float bf2f(u16 h) {
  return __uint_as_float(((unsigned)h) << 16);
}
__device__ __forceinline__ void gl2lds16(const u16* g, u16* l) {
  __builtin_amdgcn_global_load_lds((const __attribute__((address_space(1))) void*)g,
                                   (__attribute__((address_space(3))) void*)l, 16, 0, 0);
}

// ---------------- int degree ----------------
__global__ __launch_bounds__(256) void degcnt_k(const int* __restrict__ dst, int* __restrict__ cnt) {
  int e = blockIdx.x * 256 + threadIdx.x;
  if (e < EVAL) atomicAdd(&cnt[dst[e]], 1);
}

// ---------------- exclusive scan over cnt[NKVAL] -> off[NKVAL+1], single block ----------------
__global__ __launch_bounds__(1024) void scan_k(const int* __restrict__ cnt, int* __restrict__ off) {
  __shared__ int part[1024];
  const int t = threadIdx.x;
  const int base = t * 32;
  int local[32];
  int s = 0;
#pragma unroll
  for (int i = 0; i < 32; i++) { local[i] = s; s += cnt[base + i]; }
  part[t] = s;
  __syncthreads();
  for (int d = 1; d < 1024; d <<= 1) {
    int v = (t >= d) ? part[t - d] : 0;
    __syncthreads();
    part[t] += v;
    __syncthreads();
  }
  int pre = (t == 0) ? 0 : part[t - 1];
#pragma unroll
  for (int i = 0; i < 32; i++) off[base + i] = pre + local[i];
  if (t == 1023) off[NKVAL] = pre + s;
}

// ---------------- scatter edges into CSR-by-dst ----------------
__global__ __launch_bounds__(256) void scatter_k(const int* __restrict__ src, const int* __restrict__ dst,
                                                 const int* __restrict__ off, int* __restrict__ cur,
                                                 int* __restrict__ srcs_sorted) {
  int e = blockIdx.x * 256 + threadIdx.x;
  if (e < EVAL) {
    int d = dst[e];
    int p = atomicAdd(&cur[d], 1);
    srcs_sorted[off[d] + p] = src[e];
  }
}

// ---------------- layer-0 aggregation via CSR (no atomics) ----------------
__global__ __launch_bounds__(256) void agg0_csr(const int* __restrict__ off, const int* __restrict__ srcs,
                                                const float* __restrict__ known, float* __restrict__ m0) {
  int d = blockIdx.x * 256 + threadIdx.x;
  if (d >= NKVAL) return;
  int b = off[d], e = off[d + 1];
  float a0 = 0.f, a1 = 0.f, a2 = 0.f;
  for (int i = b; i < e; i++) {
    int s = srcs[i];
    a0 += known[s * 3 + 0];
    a1 += known[s * 3 + 1];
    a2 += known[s * 3 + 2];
  }
  m0[d * 3 + 0] = a0;
  m0[d * 3 + 1] = a1;
  m0[d * 3 + 2] = a2;
}

// ---------------- K=3 dense: Y = relu((X[/cnt]) @ W[3,512] + b) -> bf16, vectorized ----------------
__global__ __launch_bounds__(256) void k3_dense(const float* __restrict__ X, const int* __restrict__ cnt,
                                                const float* __restrict__ W, const float* __restrict__ Bb,
                                                u16* __restrict__ Y, int M) {
  int id = blockIdx.x * 256 + threadIdx.x;  // M*64 threads, 8 outputs each
  if (id >= M * 64) return;
  int i = id >> 6, j0 = (id & 63) * 8;
  float x0 = X[i * 3 + 0], x1 = X[i * 3 + 1], x2 = X[i * 3 + 2];
  if (cnt) {
    float inv = 1.0f / fmaxf((float)cnt[i], 1.0f);
    x0 *= inv; x1 *= inv; x2 *= inv;
  }
  u16x8 o;
#pragma unroll
  for (int j = 0; j < 8; j++) {
    float v = fmaf(x0, W[j0 + j], Bb[j0 + j]);
    v = fmaf(x1, W[512 + j0 + j], v);
    v = fmaf(x2, W[1024 + j0 + j], v);
    o[j] = f2bf(fmaxf(v, 0.0f));
  }
  *(u16x8*)(Y + (size_t)i * 512 + j0) = o;
}

// ---------------- GCN aggregation via CSR: wave per dst node, regs only ----------------
__global__ __launch_bounds__(256) void agg_csr(const u16* __restrict__ H, const int* __restrict__ off,
                                               const int* __restrict__ srcs, u16* __restrict__ Mo) {
  const int raw = blockIdx.x;
  const int nb = (raw & 7) * 1024 + (raw >> 3);
  const int node = nb * 4 + (threadIdx.x >> 6);
  const int lane = threadIdx.x & 63;
  const int beg = off[node], end = off[node + 1];
  const int c0 = lane * 8;
  float acc[8] = {0, 0, 0, 0, 0, 0, 0, 0};
  int e = beg;
  for (; e + 4 <= end; e += 4) {
    int s0 = srcs[e], s1 = srcs[e + 1], s2 = srcs[e + 2], s3 = srcs[e + 3];
    u16x8 h0 = *(const u16x8*)(H + (size_t)s0 * 512 + c0);
    u16x8 h1 = *(const u16x8*)(H + (size_t)s1 * 512 + c0);
    u16x8 h2 = *(const u16x8*)(H + (size_t)s2 * 512 + c0);
    u16x8 h3 = *(const u16x8*)(H + (size_t)s3 * 512 + c0);
#pragma unroll
    for (int j = 0; j < 8; j++)
      acc[j] += (bf2f(h0[j]) + bf2f(h1[j])) + (bf2f(h2[j]) + bf2f(h3[j]));
  }
  for (; e < end; e++) {
    int s = srcs[e];
    u16x8 hv = *(const u16x8*)(H + (size_t)s * 512 + c0);
#pragma unroll
    for (int j = 0; j < 8; j++) acc[j] += bf2f(hv[j]);
  }
  float inv = 1.0f / fmaxf((float)(end - beg), 1.0f);
  u16x8 o;
#pragma unroll
  for (int j = 0; j < 8; j++) o[j] = f2bf(acc[j] * inv);
  *(u16x8*)(Mo + (size_t)node * 512 + c0) = o;
}

// ---------------- weight cast+transpose x2: WT[n][k] = bf16(W[k][n]) ----------------
__global__ __launch_bounds__(256) void wcast2_k(const float* __restrict__ s0, const float* __restrict__ s1,
                                                u16* __restrict__ d0, u16* __restrict__ d1) {
  const float* W = (blockIdx.z == 0) ? s0 : s1;
  u16* WT = (blockIdx.z == 0) ? d0 : d1;
  __shared__ u16 tile[64][72];
  const int k0 = blockIdx.y * 64, n0 = blockIdx.x * 64, t = threadIdx.x;
#pragma unroll
  for (int i = 0; i < 16; i++) {
    int kk = (t >> 6) * 16 + i, nn = t & 63;
    tile[nn][kk] = f2bf(W[(size_t)(k0 + kk) * 512 + n0 + nn]);
  }
  __syncthreads();
#pragma unroll
  for (int i = 0; i < 16; i++) {
    int nn = (t >> 6) * 16 + i, kk = t & 63;
    WT[(size_t)(n0 + nn) * 512 + k0 + kk] = tile[nn][kk];
  }
}

// ---------------- fragment-major B pack: F[kblk][nblk][lane][8] = bf16(W[k][n]) ----------------
__global__ __launch_bounds__(256) void wfrag_k(const float* __restrict__ W, u16* __restrict__ F) {
  int id = blockIdx.x * 256 + threadIdx.x;   // 16*32*64 = 32768
  int lane = id & 63, nblk = (id >> 6) & 31, kblk = id >> 11;
  int k0 = kblk * 32 + (lane >> 4) * 8;
  int n = nblk * 16 + (lane & 15);
  u16x8 o;
#pragma unroll
  for (int j = 0; j < 8; j++) o[j] = f2bf(W[(size_t)(k0 + j) * 512 + n]);
  *(u16x8*)(F + (size_t)id * 8) = o;
}

// ---------------- pooling ----------------
__global__ __launch_bounds__(256) void pool_k(const u16* __restrict__ H2, float* __restrict__ pooled) {
  __shared__ float red[256][8];
  const int g = blockIdx.y, chunk = blockIdx.x, t = threadIdx.x;
  const int cg = t & 63, rs = t >> 6;
  const int r0 = chunk * 128;
  float a[8] = {0, 0, 0, 0, 0, 0, 0, 0};
  for (int r = r0 + rs; r < r0 + 128; r += 4) {
    u16x8 v = *(const u16x8*)(H2 + ((size_t)(g << 10) + r) * 512 + cg * 8);
#pragma unroll
    for (int j = 0; j < 8; j++) a[j] += bf2f(v[j]);
  }
#pragma unroll
  for (int j = 0; j < 8; j++) red[t][j] = a[j];
  __syncthreads();
  if (t < 64) {
#pragma unroll
    for (int j = 0; j < 8; j++) {
      float s = red[t][j] + red[t + 64][j] + red[t + 128][j] + red[t + 192][j];
      atomicAdd(&pooled[g * 512 + t * 8 + j], s * (1.0f / 1024.0f));
    }
  }
}

// ---------------- field = pooled @ gc_wr + gc_br ----------------
__global__ __launch_bounds__(256) void field_k(const float* __restrict__ pooled, const float* __restrict__ wr,
                                               const float* __restrict__ br, float* __restrict__ field) {
  int id = blockIdx.x * 256 + threadIdx.x;  // 32*512
  int g = id >> 9, j = id & 511;
  float s = br[j];
  for (int k = 0; k < 512; k++) s = fmaf(pooled[g * 512 + k], wr[k * 512 + j], s);
  field[id] = s;
}

// ---------------- GCN GEMM: 256x256 tile, 4-buffer, depth-3 counted vmcnt, XOR swizzle ----------------
__global__ __launch_bounds__(512) void gemm0(const u16* __restrict__ A, const u16* __restrict__ BT,
                                             const float* __restrict__ bias, u16* __restrict__ C) {
  constexpr int K = 512;
  constexpr int NT = 16;
  __shared__ u16 As[4][256 * 32];
  __shared__ u16 Bs[4][256 * 32];
  const int t = threadIdx.x;
  const int wave = t >> 6, lane = t & 63;
  const int wr = wave >> 2, wc = wave & 3;
  const int lr = lane & 15, kg = lane >> 4;
  const int kx = (lr >> 1) & 3;
  const long bm0 = (long)blockIdx.y * 256;
  const int bn0 = blockIdx.x * 256;
  f32x4 acc[8][4] = {};
  const int arow = t >> 2;
  const int acs = (((t & 3) ^ ((t >> 3) & 3)) * 8);
  const u16* gA0 = A + (bm0 + arow) * K + acs;
  const u16* gA1 = gA0 + 128 * K;
  const u16* gB0 = BT + (long)(bn0 + arow) * K + acs;
  const u16* gB1 = gB0 + 128 * K;

  auto STAGE = [&](int tile) {
    const int b = tile & 3;
    const int kt = tile * 32;
    gl2lds16(gA0 + kt, &As[b][t * 8]);
    gl2lds16(gA1 + kt, &As[b][4096 + t * 8]);
    gl2lds16(gB0 + kt, &Bs[b][t * 8]);
    gl2lds16(gB1 + kt, &Bs[b][4096 + t * 8]);
  };

  STAGE(0);
  STAGE(1);
  STAGE(2);
  asm volatile("s_waitcnt vmcnt(8)" ::: "memory");
  __builtin_amdgcn_s_barrier();

#pragma unroll
  for (int tt = 0; tt < NT; ++tt) {
    const int b = tt & 3;
    if (tt + 3 < NT) STAGE(tt + 3);
    bf16x8 af[8], bfv[4];
#pragma unroll
    for (int i = 0; i < 8; i++)
      af[i] = *(const bf16x8*)&As[b][(wr * 128 + i * 16 + lr) * 32 + (kg ^ kx) * 8];
#pragma unroll
    for (int n = 0; n < 4; n++)
      bfv[n] = *(const bf16x8*)&Bs[b][(wc * 64 + n * 16 + lr) * 32 + (kg ^ kx) * 8];
#pragma unroll
    for (int i = 0; i < 8; i++)
#pragma unroll
      for (int n = 0; n < 4; n++)
        acc[i][n] = __builtin_amdgcn_mfma_f32_16x16x32_bf16(af[i], bfv[n], acc[i][n], 0, 0, 0);
    if (tt + 1 < NT) {
      const int last_staged = (tt + 3 < NT) ? (tt + 3) : (NT - 1);
      const int ahead = last_staged - (tt + 1);
      if (ahead >= 2)      asm volatile("s_waitcnt vmcnt(8)" ::: "memory");
      else if (ahead == 1) asm volatile("s_waitcnt vmcnt(4)" ::: "memory");
      else                 asm volatile("s_waitcnt vmcnt(0)" ::: "memory");
      __builtin_amdgcn_s_barrier();
    }
  }

  float bb[4];
#pragma unroll
  for (int n = 0; n < 4; n++) bb[n] = bias[bn0 + wc * 64 + n * 16 + lr];
#pragma unroll
  for (int i = 0; i < 8; i++)
#pragma unroll
    for (int n = 0; n < 4; n++) {
      int col = bn0 + wc * 64 + n * 16 + lr;
#pragma unroll
      for (int r2 = 0; r2 < 4; r2++) {
        long row = bm0 + wr * 128 + i * 16 + kg * 4 + r2;
        C[row * 512 + col] = f2bf(fmaxf(acc[i][n][r2] + bb[n], 0.0f));
      }
    }
}

// ---------------- fused query path v3: barrier-light ----------------
// pre-loop: t1 = relu(nodes@wt1+bt1) for all 128x512 -> zl (subtiled+swizzled, 1 barrier)
// phase 1:  acc = t1 @ wt2 (A from read-only zl, B dbuf from wt2F) -- NO barriers
//           barrier; zl overwritten with z = (acc+bt2)*field; barrier
// phase 2:  acc (reused, zeroed) = z @ wo1; epilogue wo2 reduce -> out   -- NO barriers
__global__ __launch_bounds__(512, 1) void fused_q(const float* __restrict__ nodes3,
                                                  const float* __restrict__ wt1, const float* __restrict__ bt1,
                                                  const u16* __restrict__ wt2F, const float* __restrict__ bt2,
                                                  const float* __restrict__ field, const u16* __restrict__ wo1F,
                                                  const float* __restrict__ bo1, const float* __restrict__ wo2,
                                                  const float* __restrict__ bo2, float* __restrict__ out) {
  __shared__ u16 zl[16][128 * 32];   // 128 KB: t1 during phase 1, z during phase 2
  __shared__ float redb[8 * 64 * 3]; // 6 KB epilogue reduce
  const int t = threadIdx.x;
  const int wave = t >> 6, lane = t & 63;
  const int wr = wave >> 2, wc = wave & 3;   // 2x4 wave grid; wave = 64 rows x 128 cols
  const int lr = lane & 15, kg = lane >> 4;
  const int kx = (lr >> 1) & 3;
  const long bm0 = (long)blockIdx.x * 128;
  const int g = (int)(bm0 >> 13);
  const int arow = t >> 2;
  const int acs = (((t & 3) ^ ((t >> 3) & 3)) * 8);  // source-col pre-swizzle (verified)
  const float nx = nodes3[(bm0 + arow) * 3 + 0];
  const float ny = nodes3[(bm0 + arow) * 3 + 1];
  const float nz = nodes3[(bm0 + arow) * 3 + 2];

  // ---- t1 precompute: all 16 k-blocks, barrier-free, full ILP on the wt1 loads ----
#pragma unroll
  for (int kb = 0; kb < 16; kb++) {
    const int kt = kb * 32;
    float w0[8], w1[8], w2[8], bb[8];
    const float* wp = wt1 + kt + acs;
    *(float4*)&w0[0] = *(const float4*)(wp);
    *(float4*)&w0[4] = *(const float4*)(wp + 4);
    *(float4*)&w1[0] = *(const float4*)(wp + 512);
    *(float4*)&w1[4] = *(const float4*)(wp + 516);
    *(float4*)&w2[0] = *(const float4*)(wp + 1024);
    *(float4*)&w2[4] = *(const float4*)(wp + 1028);
    *(float4*)&bb[0] = *(const float4*)(bt1 + kt + acs);
    *(float4*)&bb[4] = *(const float4*)(bt1 + kt + acs + 4);
    u16x8 o;
#pragma unroll
    for (int j = 0; j < 8; j++) {
      float v = fmaf(nx, w0[j], fmaf(ny, w1[j], fmaf(nz, w2[j], bb[j])));
      o[j] = f2bf(fmaxf(v, 0.0f));
    }
    *(u16x8*)&zl[kb][t * 8] = o;   // linear dest == Ab scheme; cols pre-swizzled via acs
  }
  __syncthreads();

  f32x4 acc[4][8] = {};
  bf16x8 bq[2][8];

  // ---- phase 1: t1 @ wt2, barrier-free ----
#pragma unroll
  for (int n = 0; n < 8; n++)
    bq[0][n] = *(const bf16x8*)(wt2F + ((size_t)((wc * 8 + n) * 64 + lane)) * 8);
#pragma unroll
  for (int tt = 0; tt < 16; ++tt) {
    bf16x8 af[4];
#pragma unroll
    for (int i = 0; i < 4; i++)
      af[i] = *(const bf16x8*)&zl[tt][(wr * 64 + i * 16 + lr) * 32 + (kg ^ kx) * 8];
    if (tt < 15) {
#pragma unroll
      for (int n = 0; n < 8; n++)
        bq[(tt + 1) & 1][n] =
            *(const bf16x8*)(wt2F + ((size_t)(((tt + 1) * 32 + wc * 8 + n) * 64 + lane)) * 8);
    }
#pragma unroll
    for (int i = 0; i < 4; i++)
#pragma unroll
      for (int n = 0; n < 8; n++)
        acc[i][n] = __builtin_amdgcn_mfma_f32_16x16x32_bf16(af[i], bq[tt & 1][n], acc[i][n], 0, 0, 0);
  }

  // ---- z = (acc + bt2) * field -> overwrite zl (WAR guarded by barriers) ----
  __syncthreads();
  {
    float bb2[8], fmv[8];
#pragma unroll
    for (int n = 0; n < 8; n++) {
      int col = wc * 128 + n * 16 + lr;
      bb2[n] = bt2[col];
      fmv[n] = field[g * 512 + col];
    }
#pragma unroll
    for (int i = 0; i < 4; i++)
#pragma unroll
      for (int n = 0; n < 8; n++) {
        int c32 = (n & 1) * 16 + lr;
        int kblk = wc * 4 + (n >> 1);
#pragma unroll
        for (int r2 = 0; r2 < 4; r2++) {
          int row = wr * 64 + i * 16 + kg * 4 + r2;
          int slot = (c32 >> 3) ^ ((row >> 1) & 3);
          zl[kblk][row * 32 + slot * 8 + (c32 & 7)] = f2bf((acc[i][n][r2] + bb2[n]) * fmv[n]);
        }
      }
  }
  __syncthreads();

  // ---- phase 2: z @ wo1, barrier-free; REUSE acc (zeroed) ----
#pragma unroll
  for (int i = 0; i < 4; i++)
#pragma unroll
    for (int n = 0; n < 8; n++) acc[i][n] = f32x4{0.f, 0.f, 0.f, 0.f};
#pragma unroll
  for (int n = 0; n < 8; n++)
    bq[0][n] = *(const bf16x8*)(wo1F + ((size_t)((wc * 8 + n) * 64 + lane)) * 8);
#pragma unroll
  for (int tt = 0; tt < 16; ++tt) {
    bf16x8 af[4];
#pragma unroll
    for (int i = 0; i < 4; i++)
      af[i] = *(const bf16x8*)&zl[tt][(wr * 64 + i * 16 + lr) * 32 + (kg ^ kx) * 8];
    if (tt < 15) {
#pragma unroll
      for (int n = 0; n < 8; n++)
        bq[(tt + 1) & 1][n] =
            *(const bf16x8*)(wo1F + ((size_t)(((tt + 1) * 32 + wc * 8 + n) * 64 + lane)) * 8);
    }
#pragma unroll
    for (int i = 0; i < 4; i++)
#pragma unroll
      for (int n = 0; n < 8; n++)
        acc[i][n] = __builtin_amdgcn_mfma_f32_16x16x32_bf16(af[i], bq[tt & 1][n], acc[i][n], 0, 0, 0);
  }

  // epilogue: z2 = relu(acc + bo1); out = z2 @ wo2 + bo2 (shfl over lr, LDS over waves)
#pragma unroll
  for (int i = 0; i < 4; i++) {
    float po[4][3] = {};
#pragma unroll
    for (int n = 0; n < 8; n++) {
      int col = wc * 128 + n * 16 + lr;
      float b3 = bo1[col];
      float wa = wo2[col * 3 + 0], wb = wo2[col * 3 + 1], wv = wo2[col * 3 + 2];
#pragma unroll
      for (int r2 = 0; r2 < 4; r2++) {
        float v = fmaxf(acc[i][n][r2] + b3, 0.0f);
        po[r2][0] = fmaf(v, wa, po[r2][0]);
        po[r2][1] = fmaf(v, wb, po[r2][1]);
        po[r2][2] = fmaf(v, wv, po[r2][2]);
      }
    }
#pragma unroll
    for (int s = 1; s < 16; s <<= 1)
#pragma unroll
      for (int r2 = 0; r2 < 4; r2++)
#pragma unroll
        for (int o = 0; o < 3; o++) po[r2][o] += __shfl_xor(po[r2][o], s, 64);
    if (lr == 0) {
#pragma unroll
      for (int r2 = 0; r2 < 4; r2++) {
        int rrow = i * 16 + kg * 4 + r2;
#pragma unroll
        for (int o = 0; o < 3; o++) redb[(wave * 64 + rrow) * 3 + o] = po[r2][o];
      }
    }
  }
  __syncthreads();
  if (t < 384) {
    int row = t / 3, o = t - row * 3;
    int wrr = row >> 6, rrow = row & 63;
    float s = bo2[o];
#pragma unroll
    for (int w = 0; w < 4; w++) s += redb[((wrr * 4 + w) * 64 + rrow) * 3 + o];
    out[(bm0 + row) * 3 + o] = s;
  }
}

extern "C" void kernel_launch(void* const* d_in, const int* in_sizes, int n_in,
                              void* d_out, int out_size, void* d_ws, size_t ws_size,
                              hipStream_t stream) {
  const float* known = (const float*)d_in[0];
  const float* nodes = (const float*)d_in[1];
  const int* esrc = (const int*)d_in[2];
  const int* edst = (const int*)d_in[3];
  const float* gc_w0 = (const float*)d_in[6];
  const float* gc_b0 = (const float*)d_in[7];
  const float* gc_w1 = (const float*)d_in[8];
  const float* gc_b1 = (const float*)d_in[9];
  const float* gc_w2 = (const float*)d_in[10];
  const float* gc_b2 = (const float*)d_in[11];
  const float* gc_wr = (const float*)d_in[12];
  const float* gc_br = (const float*)d_in[13];
  const float* wt1 = (const float*)d_in[14];
  const float* bt1 = (const float*)d_in[15];
  const float* wt2 = (const float*)d_in[16];
  const float* bt2 = (const float*)d_in[17];
  const float* wo1 = (const float*)d_in[18];
  const float* bo1 = (const float*)d_in[19];
  const float* wo2 = (const float*)d_in[20];
  const float* bo2 = (const float*)d_in[21];
  float* out = (float*)d_out;
  (void)in_sizes; (void)n_in; (void)out_size; (void)ws_size;

  char* ws = (char*)d_ws;
  size_t off_b = 0;
  auto alloc = [&](size_t n) -> void* {
    void* p = ws + off_b;
    off_b += (n + 255) & ~(size_t)255;
    return p;
  };
  u16* w1T   = (u16*)alloc(512 * 512 * 2);
  u16* w2T   = (u16*)alloc(512 * 512 * 2);
  u16* wt2F  = (u16*)alloc(512 * 512 * 2);
  u16* wo1F  = (u16*)alloc(512 * 512 * 2);
  int* cnt   = (int*)alloc(NKVAL * 4);
  int* off   = (int*)alloc((NKVAL + 1) * 4);
  int* cur   = (int*)alloc(NKVAL * 4);
  int* srcs  = (int*)alloc((size_t)EVAL * 4);
  float* m0     = (float*)alloc(NKVAL * 3 * 4);
  float* pooled = (float*)alloc(32 * 512 * 4);
  float* field  = (float*)alloc(32 * 512 * 4);
  u16* bufA = (u16*)alloc((size_t)NKVAL * 512 * 2);
  u16* bufB = (u16*)alloc((size_t)NKVAL * 512 * 2);
  u16* bufC = (u16*)alloc((size_t)NKVAL * 512 * 2);

  hipMemsetAsync(cnt, 0, NKVAL * 4, stream);
  hipMemsetAsync(cur, 0, NKVAL * 4, stream);
  hipMemsetAsync(pooled, 0, 32 * 512 * 4, stream);

  wcast2_k<<<dim3(8, 8, 2), 256, 0, stream>>>(gc_w1, gc_w2, w1T, w2T);
  wfrag_k<<<128, 256, 0, stream>>>(wt2, wt2F);
  wfrag_k<<<128, 256, 0, stream>>>(wo1, wo1F);

  degcnt_k<<<EVAL / 256, 256, 0, stream>>>(edst, cnt);
  scan_k<<<1, 1024, 0, stream>>>(cnt, off);
  scatter_k<<<EVAL / 256, 256, 0, stream>>>(esrc, edst, off, cur, srcs);
  agg0_csr<<<NKVAL / 256, 256, 0, stream>>>(off, srcs, known, m0);

  // h0 = relu((m0/deg) @ gc_w0 + b0)
  k3_dense<<<NKVAL * 64 / 256, 256, 0, stream>>>(m0, cnt, gc_w0, gc_b0, bufA, NKVAL);
  // m1 = segsum(h0[src])/deg
  agg_csr<<<NKVAL / 4, 256, 0, stream>>>(bufA, off, srcs, bufB);
  // h1 = relu(m1 @ W1 + b1)
  gemm0<<<dim3(2, NKVAL / 256), 512, 0, stream>>>(bufB, w1T, gc_b1, bufC);
  // m2
  agg_csr<<<NKVAL / 4, 256, 0, stream>>>(bufC, off, srcs, bufA);
  // h2
  gemm0<<<dim3(2, NKVAL / 256), 512, 0, stream>>>(bufA, w2T, gc_b2, bufB);
  pool_k<<<dim3(8, 32), 256, 0, stream>>>(bufB, pooled);
  field_k<<<64, 256, 0, stream>>>(pooled, gc_wr, gc_br, field);

  // whole query path in one kernel
  fused_q<<<NQVAL / 128, 512, 0, stream>>>(nodes, wt1, bt1, wt2F, bt2, field, wo1F, bo1, wo2, bo2, out);
}